// Round 16
// baseline (318.544 us; speedup 1.0000x reference)
//
#include <hip/hip_runtime.h>
#include <hip/hip_bf16.h>

// ---------------------------------------------------------------------------
// GAT encoder: 3 GATConv layers, N=100K nodes, E=1.6M edges (+N self loops).
// f32 inputs/outputs, int32 edges (int64 fallback via on-device flag).
// R16: dense transforms fused into edge epilogues:
//   k_edge<4,0>: layer-0 aggregation + (bias,lrelu) + X1@W1 transform + layer-1
//                alpha dots, all in one kernel (feat64 eliminated, no X1 trip).
//   k_edge<1,2>: layer-2 aggregation + Agg@W2 + b2 -> d_out (k_out eliminated).
//   Fused kernels are grid-stride (2048 blocks) so the 16KB W LDS stage is
//   amortized (~49 nodes/block). Block stages the 4 result rows in LDS,
//   then feat64-style matvec (b32 W conflict-free + b128 X broadcast).
//   k_init also zeroes gcnt/flag/ovcnt (memsets dropped). 11 -> 7 dispatches.
// Buffers: Hb0=A, Hb1=B, Xb2=A (Hb0 dead by then); asn0/1/2 separate (race-free).
// ---------------------------------------------------------------------------

#define LRELU(x, a) fmaxf((x), (a) * (x))
typedef unsigned int u32;
typedef unsigned short u16;

#define NBUCKET 256
#define CAP_A 12288
#define OVCAP 65536

__device__ __forceinline__ u16 f2bf(float f) {
    u32 u = __float_as_uint(f);
    return (u16)((u + 0x7FFF + ((u >> 16) & 1)) >> 16);  // RNE, finite data
}

// merged: zero gcnt/flag/ovcnt + edge-dtype detect + va/vd precompute
__global__ __launch_bounds__(1024) void k_init(const int* __restrict__ eraw, int e,
                                               int* __restrict__ flag, int* __restrict__ gcnt,
                                               const float* __restrict__ W2,
                                               const float* __restrict__ as2,
                                               const float* __restrict__ ad2,
                                               float* __restrict__ va, float* __restrict__ vd) {
    int i = threadIdx.x;
    if (i < NBUCKET) gcnt[i] = 0;
    if (i >= NBUCKET && i < NBUCKET + 2) flag[i - NBUCKET ? 1 : 0] = 0;  // flag[0], flag[1]
    __syncthreads();
    long long step = (long long)e / 1024;
    if (step == 0) step = 1;
    long long pos = 2LL * (i * step) + 1;
    if (pos < 2LL * e && eraw[pos] != 0) atomicExch(flag, 1);
    if (i < 64) {
        float sa = 0.f, sd = 0.f;
        for (int j = 0; j < 64; j++) {
            float w = W2[i * 64 + j];
            sa += w * as2[j];
            sd += w * ad2[j];
        }
        va[i] = sa;
        vd[i] = sd;
    }
}

// Pass A: append compressed keys (s | dloc<<18) into fixed-stride bucket streams.
#define ACHUNK 2048
__global__ __launch_bounds__(256) void k_passA(const int* __restrict__ eraw, int e, int etot,
                                               const int* __restrict__ flag, int n,
                                               u32* __restrict__ keys, int* __restrict__ gcnt,
                                               int2* __restrict__ ovp, int* __restrict__ ovcnt) {
    __shared__ int bcnt[NBUCKET];
    bcnt[threadIdx.x] = 0;
    __syncthreads();
    const int base = blockIdx.x * ACHUNK;
    const bool i64 = (*flag == 0);
    int s_[8], d_[8], b_[8];
    u32 key_[8];
    #pragma unroll
    for (int j = 0; j < 8; j++) {
        int i = base + j * 256 + threadIdx.x;
        if (i < etot) {
            int s, d;
            if (i < e) {
                if (i64) { s = eraw[2 * i]; d = eraw[2 * (e + i)]; }
                else     { s = eraw[i];     d = eraw[e + i]; }
            } else { s = i - e; d = i - e; }
            s_[j] = s; d_[j] = d;
            int b = (int)(((long long)d * NBUCKET) / n);
            int node_lo_b = (int)(((long long)b * n + NBUCKET - 1) / NBUCKET);
            b_[j] = b;
            key_[j] = (u32)s | ((u32)(d - node_lo_b) << 18);
            atomicAdd(&bcnt[b], 1);
        } else b_[j] = -1;
    }
    __syncthreads();
    {
        int c = bcnt[threadIdx.x];
        bcnt[threadIdx.x] = (c > 0) ? atomicAdd(&gcnt[threadIdx.x], c) : 0;
    }
    __syncthreads();
    #pragma unroll
    for (int j = 0; j < 8; j++) {
        if (b_[j] >= 0) {
            int slot = atomicAdd(&bcnt[b_[j]], 1);
            if (slot < CAP_A) {
                keys[(size_t)b_[j] * CAP_A + slot] = key_[j];
            } else {
                int ov = atomicAdd(ovcnt, 1);
                if (ov < OVCAP) ovp[ov] = make_int2(s_[j], d_[j]);
            }
        }
    }
}

// Pass B: one WG per bucket. LDS histogram + scan + scatter; streaming writes.
__global__ __launch_bounds__(256) void k_passB(const u32* __restrict__ keys,
                                               const int* __restrict__ gcnt,
                                               const int2* __restrict__ ovp,
                                               const int* __restrict__ ovcnt, int n, int etot,
                                               int* __restrict__ rowstart,
                                               int* __restrict__ csr) {
    __shared__ int lcsr[CAP_A];
    __shared__ int lscan[512];
    __shared__ int lcur[512];
    __shared__ int gscan[NBUCKET];
    const int b = blockIdx.x;
    const int tid = threadIdx.x;
    const int node_lo = (int)(((long long)b * n + NBUCKET - 1) / NBUCKET);
    const int node_hi = (int)(((long long)(b + 1) * n + NBUCKET - 1) / NBUCKET);
    const int nodes = node_hi - node_lo;          // <= 391 < 512
    const int cnt_total = gcnt[b];
    const int stored = min(cnt_total, CAP_A);
    const int nov = min(*ovcnt, OVCAP);

    gscan[tid] = gcnt[tid];
    __syncthreads();
    #pragma unroll
    for (int o = 1; o < NBUCKET; o <<= 1) {
        int v = (tid >= o) ? gscan[tid - o] : 0;
        __syncthreads();
        gscan[tid] += v;
        __syncthreads();
    }
    const int bucket_base = (b == 0) ? 0 : gscan[b - 1];

    lscan[tid] = 0; lscan[tid + 256] = 0;
    __syncthreads();
    for (int i = tid; i < stored; i += 256) {
        int dloc = keys[(size_t)b * CAP_A + i] >> 18;
        atomicAdd(&lscan[dloc], 1);
    }
    for (int i = tid; i < nov; i += 256) {
        int d = ovp[i].y;
        if (d >= node_lo && d < node_hi) atomicAdd(&lscan[d - node_lo], 1);
    }
    __syncthreads();
    #pragma unroll
    for (int o = 1; o < 512; o <<= 1) {
        int i0 = tid, i1 = tid + 256;
        int v0 = (i0 >= o) ? lscan[i0 - o] : 0;
        int v1 = (i1 >= o) ? lscan[i1 - o] : 0;
        __syncthreads();
        lscan[i0] += v0; lscan[i1] += v1;
        __syncthreads();
    }
    #pragma unroll
    for (int t = 0; t < 2; t++) {
        int j = tid + t * 256;
        int excl = (j == 0) ? 0 : lscan[j - 1];
        lcur[j] = excl;
        if (j < nodes) rowstart[node_lo + j] = bucket_base + excl;
    }
    if (b == NBUCKET - 1 && tid == 0) rowstart[n] = etot;
    __syncthreads();
    for (int i = tid; i < stored; i += 256) {
        u32 k = keys[(size_t)b * CAP_A + i];
        int slot = atomicAdd(&lcur[k >> 18], 1);
        lcsr[slot] = (int)(k & 0x3FFFFu);
    }
    for (int i = tid; i < nov; i += 256) {
        int2 p = ovp[i];
        if (p.y >= node_lo && p.y < node_hi) {
            int slot = atomicAdd(&lcur[p.y - node_lo], 1);
            lcsr[slot] = p.x;
        }
    }
    __syncthreads();
    for (int i = tid; i < cnt_total; i += 256) csr[bucket_base + i] = lcsr[i];
}

// layer 0: h = x[N,2] @ W[2,64]; per-head (4x16) alpha dots -> bf16 H.
__global__ __launch_bounds__(256) void k_feat0(const float* __restrict__ Xin,
                                               const float* __restrict__ W,
                                               const float* __restrict__ Asrc,
                                               const float* __restrict__ Adst,
                                               u16* __restrict__ Hb, float* __restrict__ asn,
                                               float* __restrict__ adn, int n) {
    const int wv = threadIdx.x >> 6, ln = threadIdx.x & 63;
    const float w0 = W[ln], w1 = W[64 + ln];
    const float a_s = Asrc[ln], a_d = Adst[ln];
    for (int node = blockIdx.x * 4 + wv; node < n; node += gridDim.x * 4) {
        float x0 = Xin[node * 2 + 0], x1 = Xin[node * 2 + 1];
        float acc = fmaf(x1, w1, x0 * w0);
        float ts = acc * a_s, td = acc * a_d;
        #pragma unroll
        for (int o = 1; o < 16; o <<= 1) {
            ts += __shfl_xor(ts, o, 16);
            td += __shfl_xor(td, o, 16);
        }
        Hb[node * 64 + ln] = f2bf(acc);
        if ((ln & 15) == 0) {
            asn[node * 4 + (ln >> 4)] = ts;
            adn[node * 4 + (ln >> 4)] = td;
        }
    }
}

// Fused segment softmax + aggregation (+fused dense transform for modes 0/2).
// OUTMODE 0: agg(Hb0) -> leaky(.+b,0.01) -> row @ Wt -> outHb(bf16)+outAsn/outAdn
// OUTMODE 1: agg(Hb1) -> leaky(.+b,0.01) -> bf16 Outb + alpha2 dots (va/vd)
// OUTMODE 2: agg(Xb2) -> row @ Wt + bias -> OutF (f32, final output)
// NOTE: EDGE_BODY local is s_e (R14 lesson: never shadow the macro arg).
#define EDGE_BODY(SRC)                                                        \
    {                                                                         \
        int s_e = (SRC);                                                      \
        float l = LRELU(asn[s_e * HEADS + head] + adme, 0.2f);                \
        float w = __expf(l);                                                  \
        sw += w;                                                              \
        uint4 hv = ((const uint4*)Hb)[s_e * 8 + q];                           \
        v2f w2 = {w, w};                                                      \
        v2f h;                                                                \
        h.x = __uint_as_float(hv.x << 16);                                    \
        h.y = __uint_as_float(hv.x & 0xffff0000u);                            \
        p0 += w2 * h;                                                         \
        h.x = __uint_as_float(hv.y << 16);                                    \
        h.y = __uint_as_float(hv.y & 0xffff0000u);                            \
        p1 += w2 * h;                                                         \
        h.x = __uint_as_float(hv.z << 16);                                    \
        h.y = __uint_as_float(hv.z & 0xffff0000u);                            \
        p2 += w2 * h;                                                         \
        h.x = __uint_as_float(hv.w << 16);                                    \
        h.y = __uint_as_float(hv.w & 0xffff0000u);                            \
        p3 += w2 * h;                                                         \
    }

template <int HEADS, int OUTMODE>
__global__ __launch_bounds__(256) void k_edge(const u16* __restrict__ Hb,
                                              const float* __restrict__ asn,
                                              const float* __restrict__ adn,
                                              const int* __restrict__ rowstart,
                                              const int* __restrict__ csr,
                                              const float* __restrict__ bias,
                                              const float* __restrict__ Wt,
                                              const float* __restrict__ ats,
                                              const float* __restrict__ atd,
                                              u16* __restrict__ outHb,
                                              float* __restrict__ outAsn,
                                              float* __restrict__ outAdn,
                                              u16* __restrict__ Outb,
                                              const float* __restrict__ va,
                                              const float* __restrict__ vd,
                                              float* __restrict__ asn2,
                                              float* __restrict__ adn2,
                                              float* __restrict__ OutF, int n) {
    typedef float v2f __attribute__((ext_vector_type(2)));
    constexpr bool COOP = (OUTMODE != 1);
    __shared__ float Ws[COOP ? 4096 : 1];
    __shared__ __align__(16) float Xs[COOP ? 4 : 1][COOP ? 64 : 1];
    if constexpr (COOP) {
        for (int i = threadIdx.x; i < 4096; i += 256) Ws[i] = Wt[i];
        __syncthreads();
    }
    const int wv = threadIdx.x >> 6, ln = threadIdx.x & 63;
    const int g = ln >> 3, q = ln & 7;
    const int head = (HEADS == 4) ? (q >> 1) : 0;

    for (int base = blockIdx.x * 4; base < n; base += gridDim.x * 4) {
        const int node = base + wv;
        const bool valid = node < n;

        int start = 0, end = 0;
        float adme = 0.f;
        if (valid) {
            start = rowstart[node];
            end = rowstart[node + 1];
            adme = adn[node * HEADS + head];
        }
        const int deg = end - start;
        int sload = (ln < deg) ? csr[start + ln] : 0;

        v2f p0 = {0.f, 0.f}, p1 = {0.f, 0.f}, p2 = {0.f, 0.f}, p3 = {0.f, 0.f};
        float sw = 0.f;
        const int mainE = deg < 64 ? deg : 64;
        const int T = (mainE + 7) >> 3;  // wave-uniform trip count
        for (int t = 0; t < T; t++) {
            int i = g + 8 * t;           // <= 63: valid, ACTIVE source lane
            int s = __shfl(sload, i);
            if (i < mainE) EDGE_BODY(s)
        }
        for (int eg = start + 64 + g; eg < end; eg += 8) EDGE_BODY(csr[eg])

        #pragma unroll
        for (int o = 8; o < 64; o <<= 1) {
            p0.x += __shfl_xor(p0.x, o); p0.y += __shfl_xor(p0.y, o);
            p1.x += __shfl_xor(p1.x, o); p1.y += __shfl_xor(p1.y, o);
            p2.x += __shfl_xor(p2.x, o); p2.y += __shfl_xor(p2.y, o);
            p3.x += __shfl_xor(p3.x, o); p3.y += __shfl_xor(p3.y, o);
            sw += __shfl_xor(sw, o);
        }
        const float inv = 1.0f / sw;  // every lane now holds full sums
        float r0 = p0.x * inv, r1 = p0.y * inv, r2 = p1.x * inv, r3 = p1.y * inv;
        float r4 = p2.x * inv, r5 = p2.y * inv, r6 = p3.x * inv, r7 = p3.y * inv;

        if constexpr (OUTMODE == 1) {
            if (valid && ln < 8) {
                const float4 bA = ((const float4*)bias)[2 * q];
                const float4 bB = ((const float4*)bias)[2 * q + 1];
                r0 = LRELU(r0 + bA.x, 0.01f); r1 = LRELU(r1 + bA.y, 0.01f);
                r2 = LRELU(r2 + bA.z, 0.01f); r3 = LRELU(r3 + bA.w, 0.01f);
                r4 = LRELU(r4 + bB.x, 0.01f); r5 = LRELU(r5 + bB.y, 0.01f);
                r6 = LRELU(r6 + bB.z, 0.01f); r7 = LRELU(r7 + bB.w, 0.01f);
                uint4 pb;
                pb.x = (u32)f2bf(r0) | ((u32)f2bf(r1) << 16);
                pb.y = (u32)f2bf(r2) | ((u32)f2bf(r3) << 16);
                pb.z = (u32)f2bf(r4) | ((u32)f2bf(r5) << 16);
                pb.w = (u32)f2bf(r6) | ((u32)f2bf(r7) << 16);
                ((uint4*)Outb)[node * 8 + q] = pb;
                const float4 vA = ((const float4*)va)[2 * q];
                const float4 vB = ((const float4*)va)[2 * q + 1];
                const float4 dA = ((const float4*)vd)[2 * q];
                const float4 dB = ((const float4*)vd)[2 * q + 1];
                float ts = r0 * vA.x + r1 * vA.y + r2 * vA.z + r3 * vA.w +
                           r4 * vB.x + r5 * vB.y + r6 * vB.z + r7 * vB.w;
                float td = r0 * dA.x + r1 * dA.y + r2 * dA.z + r3 * dA.w +
                           r4 * dB.x + r5 * dB.y + r6 * dB.z + r7 * dB.w;
                ts += __shfl_xor(ts, 1, 8); td += __shfl_xor(td, 1, 8);
                ts += __shfl_xor(ts, 2, 8); td += __shfl_xor(td, 2, 8);
                ts += __shfl_xor(ts, 4, 8); td += __shfl_xor(td, 4, 8);
                if (ln == 0) { asn2[node] = ts; adn2[node] = td; }
            }
        } else {
            if constexpr (OUTMODE == 0) {
                // bias + leaky BEFORE the transform (this is X1)
                const float4 bA = ((const float4*)bias)[2 * q];
                const float4 bB = ((const float4*)bias)[2 * q + 1];
                r0 = LRELU(r0 + bA.x, 0.01f); r1 = LRELU(r1 + bA.y, 0.01f);
                r2 = LRELU(r2 + bA.z, 0.01f); r3 = LRELU(r3 + bA.w, 0.01f);
                r4 = LRELU(r4 + bB.x, 0.01f); r5 = LRELU(r5 + bB.y, 0.01f);
                r6 = LRELU(r6 + bB.z, 0.01f); r7 = LRELU(r7 + bB.w, 0.01f);
            }
            // stage this wave's row (lanes 0..7 hold channels 8*ln..8*ln+7)
            if (valid && ln < 8) {
                float* xr = &Xs[wv][8 * ln];
                xr[0] = r0; xr[1] = r1; xr[2] = r2; xr[3] = r3;
                xr[4] = r4; xr[5] = r5; xr[6] = r6; xr[7] = r7;
            }
            __syncthreads();
            float acc = 0.f;
            if (valid) {
                #pragma unroll
                for (int k4 = 0; k4 < 16; k4++) {
                    float4 xk = *(const float4*)&Xs[wv][k4 * 4];
                    acc = fmaf(xk.x, Ws[(4 * k4 + 0) * 64 + ln], acc);
                    acc = fmaf(xk.y, Ws[(4 * k4 + 1) * 64 + ln], acc);
                    acc = fmaf(xk.z, Ws[(4 * k4 + 2) * 64 + ln], acc);
                    acc = fmaf(xk.w, Ws[(4 * k4 + 3) * 64 + ln], acc);
                }
            }
            __syncthreads();  // protect Xs before next iteration's staging
            if (valid) {
                if constexpr (OUTMODE == 0) {
                    float ts = acc * ats[ln], td = acc * atd[ln];
                    #pragma unroll
                    for (int o = 1; o < 16; o <<= 1) {
                        ts += __shfl_xor(ts, o, 16);
                        td += __shfl_xor(td, o, 16);
                    }
                    outHb[(size_t)node * 64 + ln] = f2bf(acc);
                    if ((ln & 15) == 0) {
                        outAsn[node * 4 + (ln >> 4)] = ts;
                        outAdn[node * 4 + (ln >> 4)] = td;
                    }
                } else {
                    OutF[(size_t)node * 64 + ln] = acc + bias[ln];
                }
            }
        }
    }
}

extern "C" void kernel_launch(void* const* d_in, const int* in_sizes, int n_in, void* d_out,
                              int out_size, void* d_ws, size_t ws_size, hipStream_t stream) {
    const float* x = (const float*)d_in[0];
    const int* eraw = (const int*)d_in[1];
    const float* W0 = (const float*)d_in[2];
    const float* as0 = (const float*)d_in[3];
    const float* ad0 = (const float*)d_in[4];
    const float* b0 = (const float*)d_in[5];
    const float* W1 = (const float*)d_in[6];
    const float* as1 = (const float*)d_in[7];
    const float* ad1 = (const float*)d_in[8];
    const float* b1 = (const float*)d_in[9];
    const float* W2 = (const float*)d_in[10];
    const float* as2 = (const float*)d_in[11];
    const float* ad2 = (const float*)d_in[12];
    const float* b2 = (const float*)d_in[13];

    const int n = in_sizes[0] / 2;   // x [N,2]
    const int e = in_sizes[1] / 2;   // edge_index [2,E]
    const int etot = e + n;

    char* wp = (char*)d_ws;
    size_t off = 0;
    auto take = [&](size_t bytes) -> void* {
        void* p = wp + off;
        off = (off + bytes + 255) & ~(size_t)255;
        return p;
    };
    // A and B: two bf16 [N,64] buffers; keys (12.6MB) alias A+B start (dead
    // before k_feat0 writes A).
    size_t hsz = (size_t)n * 64 * 2;
    size_t psz = (size_t)NBUCKET * CAP_A * 4;
    size_t usz = 2 * hsz > psz ? 2 * hsz : psz;
    char* ubase   = (char*)take(usz);
    u16* A        = (u16*)ubase;               // Hb0, later Xb2
    u16* B        = (u16*)(ubase + hsz);       // Hb1
    u32* keys     = (u32*)ubase;
    float* asn0   = (float*)take((size_t)n * 4 * 4);
    float* adn0   = (float*)take((size_t)n * 4 * 4);
    float* asn1   = (float*)take((size_t)n * 4 * 4);
    float* adn1   = (float*)take((size_t)n * 4 * 4);
    float* asn2   = (float*)take((size_t)n * 4);
    float* adn2   = (float*)take((size_t)n * 4);
    int* rowstart = (int*)take((size_t)(n + 1) * 4);
    int* gcnt     = (int*)take(NBUCKET * 4);
    int* flag     = (int*)take(256);           // flag[0]=dtype, flag[1]=ovcnt
    int* ovcnt    = flag + 1;
    float* va     = (float*)take(64 * 4);
    float* vd     = (float*)take(64 * 4);
    int2* ovp     = (int2*)take((size_t)OVCAP * 8);
    int* csr      = (int*)take((size_t)etot * 4);
    (void)ws_size;

    k_init<<<1, 1024, 0, stream>>>(eraw, e, flag, gcnt, W2, as2, ad2, va, vd);
    k_passA<<<(etot + ACHUNK - 1) / ACHUNK, 256, 0, stream>>>(eraw, e, etot, flag, n, keys,
                                                              gcnt, ovp, ovcnt);
    k_passB<<<NBUCKET, 256, 0, stream>>>(keys, gcnt, ovp, ovcnt, n, etot, rowstart, csr);

    const int nodeBlocks4 = (n + 3) / 4;
    const int coopBlocks = 2048;  // grid-stride; W staged once per block

    // layer 0 feat: x @ W0 -> Hb0(A) + asn0/adn0
    k_feat0<<<nodeBlocks4, 256, 0, stream>>>(x, W0, as0, ad0, A, asn0, adn0, n);
    // layer 0 edge + fused layer-1 transform: gather A -> Hb1(B) + asn1/adn1
    k_edge<4, 0><<<coopBlocks, 256, 0, stream>>>(A, asn0, adn0, rowstart, csr, b0, W1, as1,
                                                 ad1, B, asn1, adn1, nullptr, nullptr,
                                                 nullptr, nullptr, nullptr, nullptr, n);
    // layer 1 edge: gather B -> Xb2(A) + alpha2 dots (va/vd) -> asn2/adn2
    k_edge<4, 1><<<nodeBlocks4, 256, 0, stream>>>(B, asn1, adn1, rowstart, csr, b1, nullptr,
                                                  nullptr, nullptr, nullptr, nullptr, nullptr,
                                                  A, va, vd, asn2, adn2, nullptr, n);
    // layer 2 edge + fused W2 projection: gather A -> d_out (f32)
    k_edge<1, 2><<<coopBlocks, 256, 0, stream>>>(A, asn2, adn2, rowstart, csr, b2, W2, nullptr,
                                                 nullptr, nullptr, nullptr, nullptr, nullptr,
                                                 nullptr, nullptr, nullptr, nullptr,
                                                 (float*)d_out, n);
}

// Round 17
// 294.558 us; speedup vs baseline: 1.0814x; 1.0814x over previous
//
#include <hip/hip_runtime.h>
#include <hip/hip_bf16.h>

// ---------------------------------------------------------------------------
// GAT encoder: 3 GATConv layers, N=100K nodes, E=1.6M edges (+N self loops).
// f32 inputs/outputs, int32 edges (int64 fallback via on-device flag).
// R17 = R15 structure (R16's barrier-fused epilogues REVERTED: coupling the
// variable-latency gather loop to block barriers cost 73->41% VALUBusy and
// +200K bank conflicts -> 107us) + one change: X1 stored bf16 (edge<4,0>
// writes bf16; feat64 reads bf16) -> ~26MB less traffic per call.
// ---------------------------------------------------------------------------

#define LRELU(x, a) fmaxf((x), (a) * (x))
typedef unsigned int u32;
typedef unsigned short u16;

#define NBUCKET 256
#define CAP_A 12288
#define OVCAP 65536

__device__ __forceinline__ float bf2f(u16 v) { return __uint_as_float(((u32)v) << 16); }
__device__ __forceinline__ u16 f2bf(float f) {
    u32 u = __float_as_uint(f);
    return (u16)((u + 0x7FFF + ((u >> 16) & 1)) >> 16);  // RNE, finite data
}

// merged: edge-dtype detect (flag: 0=>int64, 1=>int32) + va/vd precompute
__global__ __launch_bounds__(1024) void k_init(const int* __restrict__ eraw, int e,
                                               int* __restrict__ flag,
                                               const float* __restrict__ W2,
                                               const float* __restrict__ as2,
                                               const float* __restrict__ ad2,
                                               float* __restrict__ va, float* __restrict__ vd) {
    int i = threadIdx.x;
    long long step = (long long)e / 1024;
    if (step == 0) step = 1;
    long long pos = 2LL * (i * step) + 1;
    if (pos < 2LL * e && eraw[pos] != 0) atomicExch(flag, 1);
    if (i < 64) {
        float sa = 0.f, sd = 0.f;
        for (int j = 0; j < 64; j++) {
            float w = W2[i * 64 + j];
            sa += w * as2[j];
            sd += w * ad2[j];
        }
        va[i] = sa;
        vd[i] = sd;
    }
}

// Pass A: append compressed keys (s | dloc<<18) into fixed-stride bucket streams.
#define ACHUNK 2048
__global__ __launch_bounds__(256) void k_passA(const int* __restrict__ eraw, int e, int etot,
                                               const int* __restrict__ flag, int n,
                                               u32* __restrict__ keys, int* __restrict__ gcnt,
                                               int2* __restrict__ ovp, int* __restrict__ ovcnt) {
    __shared__ int bcnt[NBUCKET];
    bcnt[threadIdx.x] = 0;
    __syncthreads();
    const int base = blockIdx.x * ACHUNK;
    const bool i64 = (*flag == 0);
    int s_[8], d_[8], b_[8];
    u32 key_[8];
    #pragma unroll
    for (int j = 0; j < 8; j++) {
        int i = base + j * 256 + threadIdx.x;
        if (i < etot) {
            int s, d;
            if (i < e) {
                if (i64) { s = eraw[2 * i]; d = eraw[2 * (e + i)]; }
                else     { s = eraw[i];     d = eraw[e + i]; }
            } else { s = i - e; d = i - e; }
            s_[j] = s; d_[j] = d;
            int b = (int)(((long long)d * NBUCKET) / n);
            int node_lo_b = (int)(((long long)b * n + NBUCKET - 1) / NBUCKET);
            b_[j] = b;
            key_[j] = (u32)s | ((u32)(d - node_lo_b) << 18);
            atomicAdd(&bcnt[b], 1);
        } else b_[j] = -1;
    }
    __syncthreads();
    {
        int c = bcnt[threadIdx.x];
        bcnt[threadIdx.x] = (c > 0) ? atomicAdd(&gcnt[threadIdx.x], c) : 0;
    }
    __syncthreads();
    #pragma unroll
    for (int j = 0; j < 8; j++) {
        if (b_[j] >= 0) {
            int slot = atomicAdd(&bcnt[b_[j]], 1);
            if (slot < CAP_A) {
                keys[(size_t)b_[j] * CAP_A + slot] = key_[j];
            } else {
                int ov = atomicAdd(ovcnt, 1);
                if (ov < OVCAP) ovp[ov] = make_int2(s_[j], d_[j]);
            }
        }
    }
}

// Pass B: one WG per bucket. LDS histogram + scan + scatter; streaming writes.
__global__ __launch_bounds__(256) void k_passB(const u32* __restrict__ keys,
                                               const int* __restrict__ gcnt,
                                               const int2* __restrict__ ovp,
                                               const int* __restrict__ ovcnt, int n, int etot,
                                               int* __restrict__ rowstart,
                                               int* __restrict__ csr) {
    __shared__ int lcsr[CAP_A];
    __shared__ int lscan[512];
    __shared__ int lcur[512];
    __shared__ int gscan[NBUCKET];
    const int b = blockIdx.x;
    const int tid = threadIdx.x;
    const int node_lo = (int)(((long long)b * n + NBUCKET - 1) / NBUCKET);
    const int node_hi = (int)(((long long)(b + 1) * n + NBUCKET - 1) / NBUCKET);
    const int nodes = node_hi - node_lo;          // <= 391 < 512
    const int cnt_total = gcnt[b];
    const int stored = min(cnt_total, CAP_A);
    const int nov = min(*ovcnt, OVCAP);

    gscan[tid] = gcnt[tid];
    __syncthreads();
    #pragma unroll
    for (int o = 1; o < NBUCKET; o <<= 1) {
        int v = (tid >= o) ? gscan[tid - o] : 0;
        __syncthreads();
        gscan[tid] += v;
        __syncthreads();
    }
    const int bucket_base = (b == 0) ? 0 : gscan[b - 1];

    lscan[tid] = 0; lscan[tid + 256] = 0;
    __syncthreads();
    for (int i = tid; i < stored; i += 256) {
        int dloc = keys[(size_t)b * CAP_A + i] >> 18;
        atomicAdd(&lscan[dloc], 1);
    }
    for (int i = tid; i < nov; i += 256) {
        int d = ovp[i].y;
        if (d >= node_lo && d < node_hi) atomicAdd(&lscan[d - node_lo], 1);
    }
    __syncthreads();
    #pragma unroll
    for (int o = 1; o < 512; o <<= 1) {
        int i0 = tid, i1 = tid + 256;
        int v0 = (i0 >= o) ? lscan[i0 - o] : 0;
        int v1 = (i1 >= o) ? lscan[i1 - o] : 0;
        __syncthreads();
        lscan[i0] += v0; lscan[i1] += v1;
        __syncthreads();
    }
    #pragma unroll
    for (int t = 0; t < 2; t++) {
        int j = tid + t * 256;
        int excl = (j == 0) ? 0 : lscan[j - 1];
        lcur[j] = excl;
        if (j < nodes) rowstart[node_lo + j] = bucket_base + excl;
    }
    if (b == NBUCKET - 1 && tid == 0) rowstart[n] = etot;
    __syncthreads();
    for (int i = tid; i < stored; i += 256) {
        u32 k = keys[(size_t)b * CAP_A + i];
        int slot = atomicAdd(&lcur[k >> 18], 1);
        lcsr[slot] = (int)(k & 0x3FFFFu);
    }
    for (int i = tid; i < nov; i += 256) {
        int2 p = ovp[i];
        if (p.y >= node_lo && p.y < node_hi) {
            int slot = atomicAdd(&lcur[p.y - node_lo], 1);
            lcsr[slot] = p.x;
        }
    }
    __syncthreads();
    for (int i = tid; i < cnt_total; i += 256) csr[bucket_base + i] = lcsr[i];
}

// layer 0: h = x[N,2] @ W[2,64]; per-head (4x16) alpha dots -> bf16 H.
__global__ __launch_bounds__(256) void k_feat0(const float* __restrict__ Xin,
                                               const float* __restrict__ W,
                                               const float* __restrict__ Asrc,
                                               const float* __restrict__ Adst,
                                               u16* __restrict__ Hb, float* __restrict__ asn,
                                               float* __restrict__ adn, int n) {
    const int wv = threadIdx.x >> 6, ln = threadIdx.x & 63;
    const float w0 = W[ln], w1 = W[64 + ln];
    const float a_s = Asrc[ln], a_d = Adst[ln];
    for (int node = blockIdx.x * 4 + wv; node < n; node += gridDim.x * 4) {
        float x0 = Xin[node * 2 + 0], x1 = Xin[node * 2 + 1];
        float acc = fmaf(x1, w1, x0 * w0);
        float ts = acc * a_s, td = acc * a_d;
        #pragma unroll
        for (int o = 1; o < 16; o <<= 1) {
            ts += __shfl_xor(ts, o, 16);
            td += __shfl_xor(td, o, 16);
        }
        Hb[node * 64 + ln] = f2bf(acc);
        if ((ln & 15) == 0) {
            asn[node * 4 + (ln >> 4)] = ts;
            adn[node * 4 + (ln >> 4)] = td;
        }
    }
}

// layer 1: h = X[N,64](bf16) @ W[64,64] -> bf16 H + per-head alpha dots.
// Blocked-LDS: W staged once/block; wave does 4 nodes/iter, X transposed in
// wave-private LDS; per k: b32 W (conflict-free) + b128 broadcast + 4 FMA.
__global__ __launch_bounds__(256) void k_feat64(const u16* __restrict__ Xin,
                                                const float* __restrict__ W,
                                                const float* __restrict__ Asrc,
                                                const float* __restrict__ Adst,
                                                u16* __restrict__ Hb, float* __restrict__ asn,
                                                float* __restrict__ adn, int n) {
    __shared__ float Ws[64 * 64];
    __shared__ __align__(16) float Xs[4][256];  // [wave][k*4 + nodeslot]
    for (int i = threadIdx.x; i < 64 * 64; i += 256) Ws[i] = W[i];
    __syncthreads();
    const int wv = threadIdx.x >> 6, ln = threadIdx.x & 63;
    const float a_s = Asrc[ln], a_d = Adst[ln];
    const int r = ln >> 4;
    const int c4 = (ln & 15) * 4;
    for (int g0 = blockIdx.x * 16 + wv * 4; g0 < n; g0 += gridDim.x * 16) {
        int node_r = g0 + r;
        ushort4 xb = (node_r < n) ? *(const ushort4*)&Xin[(size_t)node_r * 64 + c4]
                                  : make_ushort4(0, 0, 0, 0);
        Xs[wv][(c4 + 0) * 4 + r] = bf2f(xb.x);
        Xs[wv][(c4 + 1) * 4 + r] = bf2f(xb.y);
        Xs[wv][(c4 + 2) * 4 + r] = bf2f(xb.z);
        Xs[wv][(c4 + 3) * 4 + r] = bf2f(xb.w);
        float acc0 = 0.f, acc1 = 0.f, acc2 = 0.f, acc3 = 0.f;
        #pragma unroll 8
        for (int k = 0; k < 64; k++) {
            float w = Ws[k * 64 + ln];
            float4 xk = *(const float4*)&Xs[wv][k * 4];
            acc0 = fmaf(xk.x, w, acc0);
            acc1 = fmaf(xk.y, w, acc1);
            acc2 = fmaf(xk.z, w, acc2);
            acc3 = fmaf(xk.w, w, acc3);
        }
        #pragma unroll
        for (int j = 0; j < 4; j++) {
            int node = g0 + j;
            if (node >= n) break;
            float acc = (j == 0) ? acc0 : (j == 1) ? acc1 : (j == 2) ? acc2 : acc3;
            float ts = acc * a_s, td = acc * a_d;
            #pragma unroll
            for (int o = 1; o < 16; o <<= 1) {
                ts += __shfl_xor(ts, o, 16);
                td += __shfl_xor(td, o, 16);
            }
            Hb[(size_t)node * 64 + ln] = f2bf(acc);
            if ((ln & 15) == 0) {
                asn[node * 4 + (ln >> 4)] = ts;
                adn[node * 4 + (ln >> 4)] = td;
            }
        }
    }
}

// Fused segment softmax + aggregation, one wave per dst node, bf16 H gather.
// Upfront coalesced csr load (lane=edge) distributed via shfl, WAVE-UNIFORM
// trip count; use predicated by group-uniform i<mainE. Spill loop for deg>64.
// OUTMODE 0: bf16 out = leaky(acc/sum + bias, 0.01)  (layer-0 -> X1 bf16)
// OUTMODE 1: bf16 out = leaky(acc/sum + bias, 0.01)  + alpha2 dots (va/vd)
// OUTMODE 2: f32 out = acc/sum                       (layer-2 aggregation)
// NOTE: EDGE_BODY local is s_e (R14 lesson: never shadow the macro arg).
#define EDGE_BODY(SRC)                                                        \
    {                                                                         \
        int s_e = (SRC);                                                      \
        float l = LRELU(asn[s_e * HEADS + head] + adme, 0.2f);                \
        float w = __expf(l);                                                  \
        sw += w;                                                              \
        uint4 hv = ((const uint4*)Hb)[s_e * 8 + q];                           \
        v2f w2 = {w, w};                                                      \
        v2f h;                                                                \
        h.x = __uint_as_float(hv.x << 16);                                    \
        h.y = __uint_as_float(hv.x & 0xffff0000u);                            \
        p0 += w2 * h;                                                         \
        h.x = __uint_as_float(hv.y << 16);                                    \
        h.y = __uint_as_float(hv.y & 0xffff0000u);                            \
        p1 += w2 * h;                                                         \
        h.x = __uint_as_float(hv.z << 16);                                    \
        h.y = __uint_as_float(hv.z & 0xffff0000u);                            \
        p2 += w2 * h;                                                         \
        h.x = __uint_as_float(hv.w << 16);                                    \
        h.y = __uint_as_float(hv.w & 0xffff0000u);                            \
        p3 += w2 * h;                                                         \
    }

template <int HEADS, int OUTMODE>
__global__ __launch_bounds__(256) void k_edge(const u16* __restrict__ Hb,
                                              const float* __restrict__ asn,
                                              const float* __restrict__ adn,
                                              const int* __restrict__ rowstart,
                                              const int* __restrict__ csr,
                                              const float* __restrict__ bias,
                                              float4* __restrict__ Outf,
                                              u16* __restrict__ Outb,
                                              const float* __restrict__ va,
                                              const float* __restrict__ vd,
                                              float* __restrict__ asn2,
                                              float* __restrict__ adn2, int n) {
    typedef float v2f __attribute__((ext_vector_type(2)));
    const int wv = threadIdx.x >> 6, ln = threadIdx.x & 63;
    const int node = blockIdx.x * 4 + wv;
    if (node >= n) return;
    const int g = ln >> 3, q = ln & 7;
    const int head = (HEADS == 4) ? (q >> 1) : 0;
    const int start = rowstart[node], end = rowstart[node + 1];
    const int deg = end - start;
    const float adme = adn[node * HEADS + head];

    int sload = (ln < deg) ? csr[start + ln] : 0;

    v2f p0 = {0.f, 0.f}, p1 = {0.f, 0.f}, p2 = {0.f, 0.f}, p3 = {0.f, 0.f};
    float sw = 0.f;
    const int mainE = deg < 64 ? deg : 64;
    const int T = (mainE + 7) >> 3;  // wave-uniform trip count
    for (int t = 0; t < T; t++) {
        int i = g + 8 * t;           // <= 63 always: valid, ACTIVE source lane
        int s = __shfl(sload, i);
        if (i < mainE) EDGE_BODY(s)
    }
    for (int eg = start + 64 + g; eg < end; eg += 8) EDGE_BODY(csr[eg])

    #pragma unroll
    for (int o = 8; o < 64; o <<= 1) {
        p0.x += __shfl_xor(p0.x, o); p0.y += __shfl_xor(p0.y, o);
        p1.x += __shfl_xor(p1.x, o); p1.y += __shfl_xor(p1.y, o);
        p2.x += __shfl_xor(p2.x, o); p2.y += __shfl_xor(p2.y, o);
        p3.x += __shfl_xor(p3.x, o); p3.y += __shfl_xor(p3.y, o);
        sw += __shfl_xor(sw, o);
    }
    if (ln < 8) {
        const float inv = 1.0f / sw;
        float r0 = p0.x * inv, r1 = p0.y * inv, r2 = p1.x * inv, r3 = p1.y * inv;
        float r4 = p2.x * inv, r5 = p2.y * inv, r6 = p3.x * inv, r7 = p3.y * inv;
        if constexpr (OUTMODE != 2) {
            const float4 bA = ((const float4*)bias)[2 * q];
            const float4 bB = ((const float4*)bias)[2 * q + 1];
            r0 = LRELU(r0 + bA.x, 0.01f); r1 = LRELU(r1 + bA.y, 0.01f);
            r2 = LRELU(r2 + bA.z, 0.01f); r3 = LRELU(r3 + bA.w, 0.01f);
            r4 = LRELU(r4 + bB.x, 0.01f); r5 = LRELU(r5 + bB.y, 0.01f);
            r6 = LRELU(r6 + bB.z, 0.01f); r7 = LRELU(r7 + bB.w, 0.01f);
            uint4 pb;
            pb.x = (u32)f2bf(r0) | ((u32)f2bf(r1) << 16);
            pb.y = (u32)f2bf(r2) | ((u32)f2bf(r3) << 16);
            pb.z = (u32)f2bf(r4) | ((u32)f2bf(r5) << 16);
            pb.w = (u32)f2bf(r6) | ((u32)f2bf(r7) << 16);
            ((uint4*)Outb)[node * 8 + q] = pb;
            if constexpr (OUTMODE == 1) {
                const float4 vA = ((const float4*)va)[2 * q];
                const float4 vB = ((const float4*)va)[2 * q + 1];
                const float4 dA = ((const float4*)vd)[2 * q];
                const float4 dB = ((const float4*)vd)[2 * q + 1];
                float ts = r0 * vA.x + r1 * vA.y + r2 * vA.z + r3 * vA.w +
                           r4 * vB.x + r5 * vB.y + r6 * vB.z + r7 * vB.w;
                float td = r0 * dA.x + r1 * dA.y + r2 * dA.z + r3 * dA.w +
                           r4 * dB.x + r5 * dB.y + r6 * dB.z + r7 * dB.w;
                ts += __shfl_xor(ts, 1, 8); td += __shfl_xor(td, 1, 8);
                ts += __shfl_xor(ts, 2, 8); td += __shfl_xor(td, 2, 8);
                ts += __shfl_xor(ts, 4, 8); td += __shfl_xor(td, 4, 8);
                if (ln == 0) { asn2[node] = ts; adn2[node] = td; }
            }
        } else {
            float4 oA = make_float4(r0, r1, r2, r3);
            float4 oB = make_float4(r4, r5, r6, r7);
            Outf[node * 16 + 2 * q] = oA;
            Outf[node * 16 + 2 * q + 1] = oB;
        }
    }
}

// final dense: out = Agg[N,64] @ W2 + b2. Blocked-LDS like k_feat64 (f32 in).
// In-place on d_out: each wave reads its 4 rows fully before writing them.
__global__ __launch_bounds__(256) void k_out(const float* __restrict__ Agg,
                                             const float* __restrict__ W2,
                                             const float* __restrict__ b2,
                                             float* __restrict__ Out, int n) {
    __shared__ float Ws[64 * 64];
    __shared__ __align__(16) float Xs[4][256];
    for (int i = threadIdx.x; i < 64 * 64; i += 256) Ws[i] = W2[i];
    __syncthreads();
    const int wv = threadIdx.x >> 6, ln = threadIdx.x & 63;
    const float bb = b2[ln];
    const int r = ln >> 4;
    const int c4 = (ln & 15) * 4;
    for (int g0 = blockIdx.x * 16 + wv * 4; g0 < n; g0 += gridDim.x * 16) {
        int node_r = g0 + r;
        float4 xq = (node_r < n) ? *(const float4*)&Agg[(size_t)node_r * 64 + c4]
                                 : make_float4(0.f, 0.f, 0.f, 0.f);
        Xs[wv][(c4 + 0) * 4 + r] = xq.x;
        Xs[wv][(c4 + 1) * 4 + r] = xq.y;
        Xs[wv][(c4 + 2) * 4 + r] = xq.z;
        Xs[wv][(c4 + 3) * 4 + r] = xq.w;
        float acc0 = 0.f, acc1 = 0.f, acc2 = 0.f, acc3 = 0.f;
        #pragma unroll 8
        for (int k = 0; k < 64; k++) {
            float w = Ws[k * 64 + ln];
            float4 xk = *(const float4*)&Xs[wv][k * 4];
            acc0 = fmaf(xk.x, w, acc0);
            acc1 = fmaf(xk.y, w, acc1);
            acc2 = fmaf(xk.z, w, acc2);
            acc3 = fmaf(xk.w, w, acc3);
        }
        #pragma unroll
        for (int j = 0; j < 4; j++) {
            int node = g0 + j;
            if (node >= n) break;
            float acc = (j == 0) ? acc0 : (j == 1) ? acc1 : (j == 2) ? acc2 : acc3;
            Out[(size_t)node * 64 + ln] = acc + bb;
        }
    }
}

extern "C" void kernel_launch(void* const* d_in, const int* in_sizes, int n_in, void* d_out,
                              int out_size, void* d_ws, size_t ws_size, hipStream_t stream) {
    const float* x = (const float*)d_in[0];
    const int* eraw = (const int*)d_in[1];
    const float* W0 = (const float*)d_in[2];
    const float* as0 = (const float*)d_in[3];
    const float* ad0 = (const float*)d_in[4];
    const float* b0 = (const float*)d_in[5];
    const float* W1 = (const float*)d_in[6];
    const float* as1 = (const float*)d_in[7];
    const float* ad1 = (const float*)d_in[8];
    const float* b1 = (const float*)d_in[9];
    const float* W2 = (const float*)d_in[10];
    const float* as2 = (const float*)d_in[11];
    const float* ad2 = (const float*)d_in[12];
    const float* b2 = (const float*)d_in[13];

    const int n = in_sizes[0] / 2;   // x [N,2]
    const int e = in_sizes[1] / 2;   // edge_index [2,E]
    const int etot = e + n;

    char* wp = (char*)d_ws;
    size_t off = 0;
    auto take = [&](size_t bytes) -> void* {
        void* p = wp + off;
        off = (off + bytes + 255) & ~(size_t)255;
        return p;
    };
    // A/B: two bf16 [N,64] buffers; keys (12.6MB) alias them (dead before use)
    size_t hsz = (size_t)n * 64 * 2;
    size_t psz = (size_t)NBUCKET * CAP_A * 4;
    size_t usz = 2 * hsz > psz ? 2 * hsz : psz;
    char* ubase   = (char*)take(usz);
    u16* A        = (u16*)ubase;               // Hb0, later Hb1
    u16* B        = (u16*)(ubase + hsz);       // X1, later Xb2
    u32* keys     = (u32*)ubase;
    float* asn0   = (float*)take((size_t)n * 4 * 4);
    float* adn0   = (float*)take((size_t)n * 4 * 4);
    float* asn1   = (float*)take((size_t)n * 4 * 4);
    float* adn1   = (float*)take((size_t)n * 4 * 4);
    float* asn2   = (float*)take((size_t)n * 4);
    float* adn2   = (float*)take((size_t)n * 4);
    int* rowstart = (int*)take((size_t)(n + 1) * 4);
    int* gcnt     = (int*)take(NBUCKET * 4);
    int* flag     = (int*)take(256);           // flag + ovcnt
    int* ovcnt    = flag + 1;
    float* va     = (float*)take(64 * 4);
    float* vd     = (float*)take(64 * 4);
    int2* ovp     = (int2*)take((size_t)OVCAP * 8);
    int* csr      = (int*)take((size_t)etot * 4);
    (void)ws_size;

    hipMemsetAsync(gcnt, 0, NBUCKET * 4, stream);
    hipMemsetAsync(flag, 0, 256, stream);

    k_init<<<1, 1024, 0, stream>>>(eraw, e, flag, W2, as2, ad2, va, vd);
    k_passA<<<(etot + ACHUNK - 1) / ACHUNK, 256, 0, stream>>>(eraw, e, etot, flag, n, keys,
                                                              gcnt, ovp, ovcnt);
    k_passB<<<NBUCKET, 256, 0, stream>>>(keys, gcnt, ovp, ovcnt, n, etot, rowstart, csr);

    const int nodeBlocks4 = (n + 3) / 4;
    const int gemmBlocks = 2048;
    float* Xact = (float*)d_out;  // f32 Agg, finally output

    // layer 0: feat -> A; edge gather A -> X1 bf16 -> B
    k_feat0<<<nodeBlocks4, 256, 0, stream>>>(x, W0, as0, ad0, A, asn0, adn0, n);
    k_edge<4, 0><<<nodeBlocks4, 256, 0, stream>>>(A, asn0, adn0, rowstart, csr, b0,
                                                  nullptr, B, nullptr, nullptr,
                                                  nullptr, nullptr, n);
    // layer 1: feat64 read B -> Hb1(A); edge gather A -> Xb2 bf16 -> B + alpha2
    k_feat64<<<gemmBlocks, 256, 0, stream>>>(B, W1, as1, ad1, A, asn1, adn1, n);
    k_edge<4, 1><<<nodeBlocks4, 256, 0, stream>>>(A, asn1, adn1, rowstart, csr, b1,
                                                  nullptr, B, va, vd, asn2, adn2, n);
    // layer 2: edge gather B -> Agg f32 (d_out); k_out in-place
    k_edge<1, 2><<<nodeBlocks4, 256, 0, stream>>>(B, asn2, adn2, rowstart, csr, nullptr,
                                                  (float4*)Xact, nullptr, nullptr, nullptr,
                                                  nullptr, nullptr, n);
    k_out<<<gemmBlocks, 256, 0, stream>>>(Xact, W2, b2, (float*)d_out, n);
}